// Round 1
// 676.400 us; speedup vs baseline: 1.0296x; 1.0296x over previous
//
#include <hip/hip_runtime.h>
#include <hip/hip_fp16.h>

#define NUSR 100000
#define NITM 50000
#define NEDG 1000000
#define NPRED 250000
#define DD 64
#define DD2 128
#define MSG_EPS 1e-7f
#define BN_EPS 1e-5f
#define SCAN_B 1024

// CSR-build bucketing: items W=1024 (shift 10), users W=2048 (shift 11) -> 49 buckets each.
// Bucket base offsets are free: rowptr[k<<shift], captured in scan3_k.
#define KI 49
#define KU 49
#define EPB 2048   // edges per part_k block

typedef _Float16 f16x8 __attribute__((ext_vector_type(8)));
typedef float f32x4 __attribute__((ext_vector_type(4)));

// ================= CSR build (once per call; edges are layer-invariant) ==========
// R10: replaced single-pass atomic scatter (134 MB partial-line writebacks, 136us)
// with 2-level scatter: part_k (bucket partition, chunked contiguous writes) +
// scatter2_k (bucket-local scatter, lines fill in L2 before writeback).

__global__ __launch_bounds__(256) void count_k(
    const int* __restrict__ u_idx, const int* __restrict__ i_idx,
    int* __restrict__ deg_u, int* __restrict__ deg_i)
{
    int base = (blockIdx.x * 256 + threadIdx.x) * 4;
    int u[4], it[4];
    #pragma unroll
    for (int q = 0; q < 4; q++) {
        int e = base + q;
        u[q]  = (e < NEDG) ? u_idx[e] : -1;
        it[q] = (e < NEDG) ? i_idx[e] : -1;
    }
    #pragma unroll
    for (int q = 0; q < 4; q++) if (it[q] >= 0) atomicAdd(&deg_i[it[q]], 1);
    #pragma unroll
    for (int q = 0; q < 4; q++) if (u[q] >= 0) atomicAdd(&deg_u[u[q]], 1);
}

__global__ __launch_bounds__(SCAN_B) void scan1_k(
    const int* __restrict__ deg_i, const int* __restrict__ deg_u,
    int* __restrict__ part_i, int* __restrict__ part_u,
    int* __restrict__ bsum_i, int* __restrict__ bsum_u, int nbi)
{
    __shared__ int s[SCAN_B];
    const int* deg; int* partial; int* bsum; int n, bb;
    if ((int)blockIdx.x < nbi) { deg = deg_i; partial = part_i; bsum = bsum_i; n = NITM; bb = blockIdx.x; }
    else { deg = deg_u; partial = part_u; bsum = bsum_u; n = NUSR; bb = blockIdx.x - nbi; }
    int tid = threadIdx.x;
    int i = bb * SCAN_B + tid;
    s[tid] = (i < n) ? deg[i] : 0;
    __syncthreads();
    for (int off = 1; off < SCAN_B; off <<= 1) {
        int t = (tid >= off) ? s[tid - off] : 0;
        __syncthreads();
        s[tid] += t;
        __syncthreads();
    }
    if (i < n) partial[i] = s[tid];
    if (tid == SCAN_B - 1) bsum[bb] = s[tid];
}

__global__ __launch_bounds__(128) void scan2_k(
    int* __restrict__ bsum_i, int* __restrict__ bsum_u, int nbi, int nbu)
{
    __shared__ int s[128];
    int* bsum = (blockIdx.x == 0) ? bsum_i : bsum_u;
    int nb = (blockIdx.x == 0) ? nbi : nbu;
    int tid = threadIdx.x;
    s[tid] = (tid < nb) ? bsum[tid] : 0;
    __syncthreads();
    for (int off = 1; off < 128; off <<= 1) {
        int t = (tid >= off) ? s[tid - off] : 0;
        __syncthreads();
        s[tid] += t;
        __syncthreads();
    }
    if (tid < nb) bsum[tid] = (tid == 0) ? 0 : s[tid - 1];
}

__global__ __launch_bounds__(SCAN_B) void scan3_k(
    const int* __restrict__ deg_i, const int* __restrict__ deg_u,
    const int* __restrict__ part_i, const int* __restrict__ part_u,
    const int* __restrict__ bsum_i, const int* __restrict__ bsum_u,
    int* __restrict__ rowptr_i, int* __restrict__ rowptr_u,
    int* __restrict__ cur_i, int* __restrict__ cur_u,
    int* __restrict__ bcur_i, int* __restrict__ bcur_u, int nbi)
{
    const int* deg; const int* partial; const int* bsum;
    int* rowptr; int* cursor; int* bcur; int n, bb, sh;
    if ((int)blockIdx.x < nbi) {
        deg = deg_i; partial = part_i; bsum = bsum_i;
        rowptr = rowptr_i; cursor = cur_i; bcur = bcur_i; n = NITM; bb = blockIdx.x; sh = 10;
    } else {
        deg = deg_u; partial = part_u; bsum = bsum_u;
        rowptr = rowptr_u; cursor = cur_u; bcur = bcur_u; n = NUSR; bb = blockIdx.x - nbi; sh = 11;
    }
    int i = bb * SCAN_B + threadIdx.x;
    if (i < n) {
        int rs = partial[i] - deg[i] + bsum[bb];
        rowptr[i] = rs;
        cursor[i] = rs;
        if ((i & ((1 << sh) - 1)) == 0) bcur[i >> sh] = rs;  // bucket chunk cursor
    }
    if (i == 0) rowptr[n] = NEDG;
}

// ---- phase 1: partition edges into dst-bucket-major (dst,src) pair lists -------
// Per block: LDS histogram over 49 buckets, ONE global atomic per bucket to
// reserve a contiguous chunk, then write pairs into the chunk. Writes are
// ~336B contiguous bursts -> full-line HBM writebacks (vs 4B random before).
__global__ __launch_bounds__(256) void part_k(
    const int* __restrict__ u_idx, const int* __restrict__ i_idx,
    int* __restrict__ bcur_i, int* __restrict__ bcur_u,
    int2* __restrict__ pair_i, int2* __restrict__ pair_u)
{
    __shared__ int lhist_i[KI], lhist_u[KU];
    __shared__ int lbase_i[KI], lbase_u[KU];
    int tid = threadIdx.x;
    int base = blockIdx.x * EPB;
    int u[8], it[8];
    #pragma unroll
    for (int q = 0; q < 8; q++) {
        int e = base + q * 256 + tid;
        u[q]  = (e < NEDG) ? u_idx[e] : -1;
        it[q] = (e < NEDG) ? i_idx[e] : -1;
    }
    if (tid < KI) lhist_i[tid] = 0;
    if (tid >= 64 && tid < 64 + KU) lhist_u[tid - 64] = 0;
    __syncthreads();
    #pragma unroll
    for (int q = 0; q < 8; q++) if (it[q] >= 0) {
        atomicAdd(&lhist_i[it[q] >> 10], 1);
        atomicAdd(&lhist_u[u[q] >> 11], 1);
    }
    __syncthreads();
    if (tid < KI) {
        int c = lhist_i[tid];
        lbase_i[tid] = c ? atomicAdd(&bcur_i[tid], c) : 0;
    }
    if (tid >= 64 && tid < 64 + KU) {
        int k = tid - 64;
        int c = lhist_u[k];
        lbase_u[k] = c ? atomicAdd(&bcur_u[k], c) : 0;
    }
    __syncthreads();
    #pragma unroll
    for (int q = 0; q < 8; q++) if (it[q] >= 0) {
        int pi_ = atomicAdd(&lbase_i[it[q] >> 10], 1);
        pair_i[pi_] = make_int2(it[q], u[q]);
        int pu_ = atomicAdd(&lbase_u[u[q] >> 11], 1);
        pair_u[pu_] = make_int2(u[q], it[q]);
    }
}

// ---- phase 2: bucket-local scatter. Each block walks a contiguous pair chunk;
// its csr writes land in an ~80KB bucket region -> lines fill in one XCD's L2.
// XCD-chunked swizzle (1960 = 8*245 blocks) keeps each XCD's working set ~1MB.
__global__ __launch_bounds__(256) void scatter2_k(
    const int2* __restrict__ pair_i, const int2* __restrict__ pair_u,
    int* __restrict__ cur_i, int* __restrict__ cur_u,
    int* __restrict__ csr_i, int* __restrict__ csr_u)
{
    int b = blockIdx.x;
    int swz = (b & 7) * 245 + (b >> 3);   // bijective: 1960 % 8 == 0
    const int2* pair; int* cur; int* csr; int e0;
    if (swz < 980) { pair = pair_i; cur = cur_i; csr = csr_i; e0 = swz * 1024; }
    else           { pair = pair_u; cur = cur_u; csr = csr_u; e0 = (swz - 980) * 1024; }
    int base = e0 + threadIdx.x * 4;
    int2 p[4]; int ps[4];
    #pragma unroll
    for (int q = 0; q < 4; q++) {
        int e = base + q;
        p[q] = (e < NEDG) ? pair[e] : make_int2(-1, -1);
    }
    #pragma unroll
    for (int q = 0; q < 4; q++) if (p[q].x >= 0) ps[q] = atomicAdd(&cur[p[q].x], 1);
    #pragma unroll
    for (int q = 0; q < 4; q++) if (p[q].x >= 0) csr[ps[q]] = p[q].y;
}

// ========== layer-0 messages for both sides: msg = half(relu(x)+eps) =============
__global__ __launch_bounds__(256) void msg0_k(
    const float* __restrict__ xu, const float* __restrict__ xi,
    __half* __restrict__ msg_u, __half* __restrict__ msg_i)
{
    int i = blockIdx.x * 256 + threadIdx.x;
    const float* x; __half* msg; int idx;
    if (i < NUSR * 16) { x = xu; msg = msg_u; idx = i; }
    else { int j = i - NUSR * 16; if (j >= NITM * 16) return; x = xi; msg = msg_i; idx = j; }
    float4 v = ((const float4*)x)[idx];
    __half2 a = __floats2half2_rn(fmaxf(v.x, 0.f) + MSG_EPS, fmaxf(v.y, 0.f) + MSG_EPS);
    __half2 b = __floats2half2_rn(fmaxf(v.z, 0.f) + MSG_EPS, fmaxf(v.w, 0.f) + MSG_EPS);
    ((__half2*)msg)[idx * 2]     = a;
    ((__half2*)msg)[idx * 2 + 1] = b;
}

// ========== weight convert+transpose to fp16 (once per call) =====================
__global__ __launch_bounds__(256) void wconv_k(
    const float* __restrict__ W1, const float* __restrict__ W2,
    __half* __restrict__ W1t, __half* __restrict__ W2t)
{
    int idx = blockIdx.x * 256 + threadIdx.x;
    if (idx >= 6 * 8192) return;
    int m = idx >> 13, rem = idx & 8191;
    {   // W1 [64][128] -> [128][64]
        int k = rem >> 7, c = rem & 127;
        W1t[m * 8192 + c * 64 + k] = __float2half(W1[idx]);
    }
    {   // W2 [128][64] -> [64][128]
        int k = rem >> 6, c = rem & 63;
        W2t[m * 8192 + c * 128 + k] = __float2half(W2[idx]);
    }
}

// ===== FUSED (item-conv + user-conv) agg + GEMM1 (MFMA fp16) =====================
// no-max softmax (m in [eps,~6], exp safe): den=sum exp, num=sum exp*m, agg=num/den.
// Gather: round-8 form (per-row sequential, unroll-4 = 4 loads in flight).
// R9's 8-deep row-pairing REGRESSED (731->774us, pathological scheduling) — keep this.
#define UPD(u) { float2 va=__half22float2(*(__half2*)&(u).x); \
                 float2 vb=__half22float2(*(__half2*)&(u).y); \
                 float eA=__expf(va.x), eB=__expf(va.y); \
                 float eC=__expf(vb.x), eD=__expf(vb.y); \
                 dA+=eA; nA=fmaf(eA,va.x,nA); dB+=eB; nB=fmaf(eB,va.y,nB); \
                 dC+=eC; nC=fmaf(eC,vb.x,nC); dD+=eD; nD=fmaf(eD,vb.y,nD); }

__global__ __launch_bounds__(256) void aggemm1f_k(
    const __half* __restrict__ msg_i_src, const __half* __restrict__ msg_u_src,
    const float* __restrict__ xi_cur, const float* __restrict__ xu_cur,
    const int* __restrict__ rowptr_i, const int* __restrict__ rowptr_u,
    const int* __restrict__ csr_i, const int* __restrict__ csr_u,
    const __half* __restrict__ W1t_l,   // layer base: [2][128][64] f16
    const float* __restrict__ b1_l,     // [2][128]
    __half* __restrict__ h1_i, __half* __restrict__ h1_u,   // fp16 h1
    double* __restrict__ gs_l,          // [2][256] (gsum|gsq per conv)
    int gI)
{
    __shared__ _Float16 sA[64][72];      // 9.2 KB
    __shared__ _Float16 sB[128][72];     // 18.4 KB
    __shared__ float sredS[4][128];      // 2 KB
    __shared__ float sredQ[4][128];      // 2 KB

    int side = ((int)blockIdx.x < gI) ? 0 : 1;
    int bb = side ? (blockIdx.x - gI) : blockIdx.x;
    const __half* msg = side ? msg_i_src : msg_u_src;
    const float* xdst = side ? xu_cur : xi_cur;
    const int* rowptr = side ? rowptr_u : rowptr_i;
    const int* csr    = side ? csr_u : csr_i;
    const __half* W1t = W1t_l + (size_t)side * 8192;
    const float* b1   = b1_l + side * DD2;
    __half* h1        = side ? h1_u : h1_i;
    double* gsum      = gs_l + side * 256;
    double* gsq       = gsum + 128;
    int N             = side ? NUSR : NITM;

    int t = threadIdx.x;
    int r0 = bb * 64;
    for (int i = t; i < 1024; i += 256) {
        int row = i >> 3, c8 = i & 7;
        *(float4*)&sB[row][c8 * 8] = ((const float4*)W1t)[i];
    }

    int w = t >> 6, lane = t & 63, q = lane >> 4, ln = lane & 15;
    const uint2* mp = (const uint2*)msg;

    // gather + softmax-agg for this block's 64 rows, results into sA
    #pragma unroll
    for (int ii = 0; ii < 4; ii++) {
        int rr = w * 16 + ii * 4 + q;
        int r = r0 + rr;
        uint2 o = make_uint2(0u, 0u);
        if (r < N) {
            int beg = rowptr[r], end = rowptr[r + 1];
            float dA=0.f,dB=0.f,dC=0.f,dD=0.f,nA=0.f,nB=0.f,nC=0.f,nD=0.f;
            int j = beg;
            for (; j + 4 <= end; j += 4) {
                int s0=csr[j], s1=csr[j+1], s2=csr[j+2], s3=csr[j+3];
                uint2 u0 = mp[(size_t)s0*16+ln];
                uint2 u1 = mp[(size_t)s1*16+ln];
                uint2 u2 = mp[(size_t)s2*16+ln];
                uint2 u3 = mp[(size_t)s3*16+ln];
                UPD(u0) UPD(u1) UPD(u2) UPD(u3)
            }
            for (; j < end; j++) {
                uint2 u = mp[(size_t)csr[j]*16+ln];
                UPD(u)
            }
            bool nz = end > beg;
            float aA = nz ? nA/dA : 0.f;
            float aB = nz ? nB/dB : 0.f;
            float aC = nz ? nC/dC : 0.f;
            float aD = nz ? nD/dD : 0.f;
            float4 xd = ((const float4*)xdst)[(size_t)r*16 + ln];
            __half2 h01 = __floats2half2_rn(aA+xd.x, aB+xd.y);
            __half2 h23 = __floats2half2_rn(aC+xd.z, aD+xd.w);
            o.x = *(unsigned int*)&h01; o.y = *(unsigned int*)&h23;
        }
        *(uint2*)&sA[rr][ln * 4] = o;
    }
    __syncthreads();

    f16x8 afr[4][2], bfr[2][2];
    #pragma unroll
    for (int rt = 0; rt < 4; rt++)
        #pragma unroll
        for (int ks = 0; ks < 2; ks++)
            afr[rt][ks] = *(const f16x8*)&sA[rt * 16 + ln][ks * 32 + q * 8];
    #pragma unroll
    for (int ct = 0; ct < 2; ct++)
        #pragma unroll
        for (int ks = 0; ks < 2; ks++)
            bfr[ct][ks] = *(const f16x8*)&sB[w * 32 + ct * 16 + ln][ks * 32 + q * 8];

    f32x4 acc[4][2];
    #pragma unroll
    for (int rt = 0; rt < 4; rt++)
        #pragma unroll
        for (int ct = 0; ct < 2; ct++)
            acc[rt][ct] = (f32x4){0.f, 0.f, 0.f, 0.f};

    #pragma unroll
    for (int rt = 0; rt < 4; rt++)
        #pragma unroll
        for (int ct = 0; ct < 2; ct++) {
            acc[rt][ct] = __builtin_amdgcn_mfma_f32_16x16x32_f16(
                afr[rt][0], bfr[ct][0], acc[rt][ct], 0, 0, 0);
            acc[rt][ct] = __builtin_amdgcn_mfma_f32_16x16x32_f16(
                afr[rt][1], bfr[ct][1], acc[rt][ct], 0, 0, 0);
        }

    float b1c0 = b1[w * 32 + ln];
    float b1c1 = b1[w * 32 + 16 + ln];
    float ps0 = 0.f, pq0 = 0.f, ps1 = 0.f, pq1 = 0.f;
    #pragma unroll
    for (int rt = 0; rt < 4; rt++) {
        #pragma unroll
        for (int i = 0; i < 4; i++) {
            int r = r0 + rt * 16 + q * 4 + i;
            if (r < N) {
                float h0 = acc[rt][0][i] + b1c0;
                float h1v = acc[rt][1][i] + b1c1;
                h1[(size_t)r * DD2 + w * 32 + ln] = __float2half(h0);
                h1[(size_t)r * DD2 + w * 32 + 16 + ln] = __float2half(h1v);
                ps0 += h0; pq0 += h0 * h0;
                ps1 += h1v; pq1 += h1v * h1v;
            }
        }
    }
    sredS[q][w * 32 + ln] = ps0;  sredS[q][w * 32 + 16 + ln] = ps1;
    sredQ[q][w * 32 + ln] = pq0;  sredQ[q][w * 32 + 16 + ln] = pq1;
    __syncthreads();
    if (t < 128) {
        float s = 0.f, qq = 0.f;
        #pragma unroll
        for (int k = 0; k < 4; k++) { s += sredS[k][t]; qq += sredQ[k][t]; }
        atomicAdd(&gsum[t], (double)s);
        atomicAdd(&gsq[t],  (double)qq);
    }
}

// ===== FUSED GEMM2 (both convs): xnew = relu(relu(bn(h1)) @ W2 + b2) + msgs ======
__global__ __launch_bounds__(256) void gemm2f_k(
    const __half* __restrict__ h1_i, const __half* __restrict__ h1_u,
    const double* __restrict__ gs_l,
    const float* __restrict__ gamma_l, const float* __restrict__ beta_l,
    const __half* __restrict__ W2t_l, const float* __restrict__ b2_l,
    float* __restrict__ xi_new, float* __restrict__ xu_new,
    __half* __restrict__ msgi_out, __half* __restrict__ msgu_out, int gI)
{
    __shared__ _Float16 sA[64][136];    // 17.4 KB
    __shared__ _Float16 sB[64][136];    // 17.4 KB
    __shared__ float2 sss[DD2];         // 1 KB

    int side = ((int)blockIdx.x < gI) ? 0 : 1;
    int bb = side ? (blockIdx.x - gI) : blockIdx.x;
    const __half* h1   = side ? h1_u : h1_i;
    const double* gsum = gs_l + side * 256;
    const double* gsq  = gsum + 128;
    const float* gamma = gamma_l + side * DD2;
    const float* beta  = beta_l + side * DD2;
    const __half* W2t  = W2t_l + (size_t)side * 8192;
    const float* b2    = b2_l + side * DD;
    float* xnew        = side ? xu_new : xi_new;
    __half* msgout     = side ? msgu_out : msgi_out;
    int N              = side ? NUSR : NITM;

    int t = threadIdx.x;
    if (t < 128) {
        double mean = gsum[t] / (double)N;
        double var  = gsq[t] / (double)N - mean * mean;
        float inv = (float)(1.0 / sqrt(var + (double)BN_EPS));
        float sc = gamma[t] * inv;
        sss[t] = make_float2(sc, beta[t] - (float)mean * sc);
    }
    for (int i = t; i < 1024; i += 256) {
        int row = i >> 4, c8 = i & 15;
        *(float4*)&sB[row][c8 * 8] = ((const float4*)W2t)[i];
    }
    __syncthreads();

    int r0 = bb * 64;
    // stage h1 (fp16) with BN + relu -> fp16: 64 rows x 32 uint2 (4 halves each)
    for (int i = t; i < 2048; i += 256) {
        int rr = i >> 5, c4 = i & 31;
        int r = r0 + rr;
        uint2 o = make_uint2(0u, 0u);
        if (r < N) {
            uint2 hv = ((const uint2*)h1)[(size_t)r * 32 + c4];
            float2 va = __half22float2(*(__half2*)&hv.x);
            float2 vb = __half22float2(*(__half2*)&hv.y);
            float2 s0 = sss[c4 * 4], s1 = sss[c4 * 4 + 1];
            float2 s2 = sss[c4 * 4 + 2], s3 = sss[c4 * 4 + 3];
            va.x = fmaxf(fmaf(va.x, s0.x, s0.y), 0.f);
            va.y = fmaxf(fmaf(va.y, s1.x, s1.y), 0.f);
            vb.x = fmaxf(fmaf(vb.x, s2.x, s2.y), 0.f);
            vb.y = fmaxf(fmaf(vb.y, s3.x, s3.y), 0.f);
            __half2 a = __floats2half2_rn(va.x, va.y);
            __half2 b = __floats2half2_rn(vb.x, vb.y);
            o.x = *(unsigned int*)&a; o.y = *(unsigned int*)&b;
        }
        *(uint2*)&sA[rr][c4 * 4] = o;
    }
    __syncthreads();

    int w = t >> 6, lane = t & 63, q = lane >> 4, ln = lane & 15;
    f32x4 acc[4];
    #pragma unroll
    for (int rt = 0; rt < 4; rt++) acc[rt] = (f32x4){0.f, 0.f, 0.f, 0.f};

    #pragma unroll
    for (int ks = 0; ks < 4; ks++) {
        f16x8 bf = *(const f16x8*)&sB[w * 16 + ln][ks * 32 + q * 8];
        #pragma unroll
        for (int rt = 0; rt < 4; rt++) {
            f16x8 af = *(const f16x8*)&sA[rt * 16 + ln][ks * 32 + q * 8];
            acc[rt] = __builtin_amdgcn_mfma_f32_16x16x32_f16(af, bf, acc[rt], 0, 0, 0);
        }
    }

    int c = w * 16 + ln;
    float bb2 = b2[c];
    #pragma unroll
    for (int rt = 0; rt < 4; rt++) {
        #pragma unroll
        for (int i = 0; i < 4; i++) {
            int r = r0 + rt * 16 + q * 4 + i;
            if (r < N) {
                float o = fmaxf(acc[rt][i] + bb2, 0.f);
                xnew[(size_t)r * DD + c] = o;
                msgout[(size_t)r * DD + c] = __float2half(o + MSG_EPS);
            }
        }
    }
}

// ================= decoder ========================================================
__global__ __launch_bounds__(256) void decode_k(
    const float* __restrict__ xu, const float* __restrict__ xi,
    const int* __restrict__ pu, const int* __restrict__ pi,
    float* __restrict__ out)
{
    int idx = blockIdx.x * 256 + threadIdx.x;
    int b = idx >> 4, lane = idx & 15;
    if (b >= NPRED) return;
    int u = pu[b], it = pi[b];
    float4 a = ((const float4*)(xu + (size_t)u * DD))[lane];
    float4 c = ((const float4*)(xi + (size_t)it * DD))[lane];
    float s = a.x * c.x + a.y * c.y + a.z * c.z + a.w * c.w;
    #pragma unroll
    for (int off = 8; off; off >>= 1) s += __shfl_down(s, off, 16);
    if (lane == 0) out[b] = s;
}

extern "C" void kernel_launch(void* const* d_in, const int* in_sizes, int n_in,
                              void* d_out, int out_size, void* d_ws, size_t ws_size,
                              hipStream_t stream)
{
    const float* x_user = (const float*)d_in[0];
    const float* x_item = (const float*)d_in[1];
    const float* W1    = (const float*)d_in[2];   // [3][2][64][128]
    const float* b1    = (const float*)d_in[3];
    const float* gamma = (const float*)d_in[4];
    const float* beta  = (const float*)d_in[5];
    const float* W2    = (const float*)d_in[6];   // [3][2][128][64]
    const float* b2    = (const float*)d_in[7];
    const int* edge = (const int*)d_in[8];        // [2][E]
    const int* pred = (const int*)d_in[9];        // [2][B]
    float* out = (float*)d_out;

    const int* u_idx = edge;
    const int* i_idx = edge + NEDG;

    // ---- workspace bump allocator (256B aligned chunks) ----
    char* p = (char*)d_ws;
    #define ALLOC(ptr, type, count) \
        type* ptr = (type*)p; p += (((size_t)(count) * sizeof(type)) + 255) & ~(size_t)255;

    ALLOC(deg_i, int, NITM)
    ALLOC(deg_u, int, NUSR)
    ALLOC(gsumAll, double, 12 * 256)             // 6 convs x (gsum[128]|gsq[128])
    size_t zero_span = (char*)p - (char*)deg_i;
    ALLOC(part_i, int, NITM)
    ALLOC(part_u, int, NUSR)
    ALLOC(bsum_i, int, 128)
    ALLOC(bsum_u, int, 128)
    ALLOC(bcur_i, int, 64)
    ALLOC(bcur_u, int, 64)
    ALLOC(rowptr_i, int, NITM + 1)
    ALLOC(rowptr_u, int, NUSR + 1)
    ALLOC(cur_i, int, NITM)
    ALLOC(cur_u, int, NUSR)
    ALLOC(csr_i, int, NEDG)
    ALLOC(csr_u, int, NEDG)
    ALLOC(h1_i, __half, (size_t)NITM * DD2)
    ALLOC(h1_u, __half, (size_t)NUSR * DD2)
    ALLOC(W1t, __half, 6 * 8192)
    ALLOC(W2t, __half, 6 * 8192)
    ALLOC(xu0, float, (size_t)NUSR * DD)
    ALLOC(xu1, float, (size_t)NUSR * DD)
    ALLOC(xi0, float, (size_t)NITM * DD)
    ALLOC(xi1, float, (size_t)NITM * DD)
    ALLOC(msg_u, __half, (size_t)NUSR * DD)
    ALLOC(msg_i0, __half, (size_t)NITM * DD)
    ALLOC(msg_i1, __half, (size_t)NITM * DD)
    #undef ALLOC
    float* xu_buf[2] = {xu0, xu1};
    float* xi_buf[2] = {xi0, xi1};

    // pair lists (phase-1 output) alias h1 buffers: pairs are consumed by
    // scatter2_k strictly BEFORE aggemm1f_k first writes h1 (same stream).
    // pair_i needs 8MB <= h1_i's 12.8MB; pair_u 8MB <= h1_u's 25.6MB.
    int2* pair_i = (int2*)h1_i;
    int2* pair_u = (int2*)h1_u;

    // ---- CSR build + converts (once; reused by all 3 layers) ----
    hipMemsetAsync(deg_i, 0, zero_span, stream);
    int eb4 = (NEDG / 4 + 255) / 256;
    count_k<<<eb4, 256, 0, stream>>>(u_idx, i_idx, deg_u, deg_i);

    int nbi = (NITM + SCAN_B - 1) / SCAN_B;   // 49
    int nbu = (NUSR + SCAN_B - 1) / SCAN_B;   // 98
    scan1_k<<<nbi + nbu, SCAN_B, 0, stream>>>(deg_i, deg_u, part_i, part_u,
                                              bsum_i, bsum_u, nbi);
    scan2_k<<<2, 128, 0, stream>>>(bsum_i, bsum_u, nbi, nbu);
    scan3_k<<<nbi + nbu, SCAN_B, 0, stream>>>(deg_i, deg_u, part_i, part_u,
                                              bsum_i, bsum_u, rowptr_i, rowptr_u,
                                              cur_i, cur_u, bcur_i, bcur_u, nbi);
    int pb = (NEDG + EPB - 1) / EPB;          // 489
    part_k<<<pb, 256, 0, stream>>>(u_idx, i_idx, bcur_i, bcur_u, pair_i, pair_u);
    scatter2_k<<<1960, 256, 0, stream>>>(pair_i, pair_u, cur_i, cur_u, csr_i, csr_u);

    wconv_k<<<(6 * 8192 + 255) / 256, 256, 0, stream>>>(W1, W2, W1t, W2t);
    msg0_k<<<((NUSR + NITM) * 16 + 255) / 256, 256, 0, stream>>>(x_user, x_item,
                                                                 msg_u, msg_i0);

    // ---- 3 layers, each = 1 fused aggemm1 + 1 fused gemm2 ----
    int gI = (NITM + 63) / 64;    // 782 item blocks
    int gU = (NUSR + 63) / 64;    // 1563 user blocks
    const float* cu = x_user;
    const float* ci = x_item;
    __half* msgi = msg_i0;
    __half* msgi_alt = msg_i1;
    for (int l = 0; l < 3; l++) {
        float* ni = xi_buf[l & 1];
        float* nu = xu_buf[l & 1];
        aggemm1f_k<<<gI + gU, 256, 0, stream>>>(
            msgi, msg_u, ci, cu, rowptr_i, rowptr_u, csr_i, csr_u,
            W1t + (size_t)l * 2 * 8192, b1 + (size_t)l * 2 * DD2,
            h1_i, h1_u, gsumAll + l * 2 * 256, gI);
        gemm2f_k<<<gI + gU, 256, 0, stream>>>(
            h1_i, h1_u, gsumAll + l * 2 * 256,
            gamma + (size_t)l * 2 * DD2, beta + (size_t)l * 2 * DD2,
            W2t + (size_t)l * 2 * 8192, b2 + (size_t)l * 2 * DD,
            ni, nu, msgi_alt, msg_u, gI);
        cu = nu; ci = ni;
        __half* tmp = msgi; msgi = msgi_alt; msgi_alt = tmp;
    }

    decode_k<<<(NPRED * 16) / 256, 256, 0, stream>>>(cu, ci, pred, pred + NPRED, out);
}

// Round 2
// 623.264 us; speedup vs baseline: 1.1174x; 1.0853x over previous
//
#include <hip/hip_runtime.h>
#include <hip/hip_fp16.h>

#define NUSR 100000
#define NITM 50000
#define NEDG 1000000
#define NPRED 250000
#define DD 64
#define DD2 128
#define MSG_EPS 1e-7f
#define BN_EPS 1e-5f
#define SCAN_B 1024

// CSR-build bucketing: items W=512 (shift 9), users W=1024 (shift 10) -> 98 buckets each.
// Pair packing (27 bits): items (dstoff<<17)|src_user; users (dstoff<<16)|src_item.
#define KI 98
#define KU 98
#define EPB 4096   // edges per part_k block

typedef _Float16 f16x8 __attribute__((ext_vector_type(8)));
typedef float f32x4 __attribute__((ext_vector_type(4)));

// ================= CSR build (once per call; edges are layer-invariant) ==========
// R10: 2-level scatter replaced atomic scatter_k (134MB partial-line WB, 136us).
// R11: phase-2 global atomics removed (one 40ms pathological dispatch seen in
// rocprof): per-bucket block with LDS cursors, packed 4B pairs. Idempotent.

__global__ __launch_bounds__(256) void count_k(
    const int* __restrict__ u_idx, const int* __restrict__ i_idx,
    int* __restrict__ deg_u, int* __restrict__ deg_i)
{
    int base = (blockIdx.x * 256 + threadIdx.x) * 4;
    int u[4], it[4];
    #pragma unroll
    for (int q = 0; q < 4; q++) {
        int e = base + q;
        u[q]  = (e < NEDG) ? u_idx[e] : -1;
        it[q] = (e < NEDG) ? i_idx[e] : -1;
    }
    #pragma unroll
    for (int q = 0; q < 4; q++) if (it[q] >= 0) atomicAdd(&deg_i[it[q]], 1);
    #pragma unroll
    for (int q = 0; q < 4; q++) if (u[q] >= 0) atomicAdd(&deg_u[u[q]], 1);
}

__global__ __launch_bounds__(SCAN_B) void scan1_k(
    const int* __restrict__ deg_i, const int* __restrict__ deg_u,
    int* __restrict__ part_i, int* __restrict__ part_u,
    int* __restrict__ bsum_i, int* __restrict__ bsum_u, int nbi)
{
    __shared__ int s[SCAN_B];
    const int* deg; int* partial; int* bsum; int n, bb;
    if ((int)blockIdx.x < nbi) { deg = deg_i; partial = part_i; bsum = bsum_i; n = NITM; bb = blockIdx.x; }
    else { deg = deg_u; partial = part_u; bsum = bsum_u; n = NUSR; bb = blockIdx.x - nbi; }
    int tid = threadIdx.x;
    int i = bb * SCAN_B + tid;
    s[tid] = (i < n) ? deg[i] : 0;
    __syncthreads();
    for (int off = 1; off < SCAN_B; off <<= 1) {
        int t = (tid >= off) ? s[tid - off] : 0;
        __syncthreads();
        s[tid] += t;
        __syncthreads();
    }
    if (i < n) partial[i] = s[tid];
    if (tid == SCAN_B - 1) bsum[bb] = s[tid];
}

__global__ __launch_bounds__(128) void scan2_k(
    int* __restrict__ bsum_i, int* __restrict__ bsum_u, int nbi, int nbu)
{
    __shared__ int s[128];
    int* bsum = (blockIdx.x == 0) ? bsum_i : bsum_u;
    int nb = (blockIdx.x == 0) ? nbi : nbu;
    int tid = threadIdx.x;
    s[tid] = (tid < nb) ? bsum[tid] : 0;
    __syncthreads();
    for (int off = 1; off < 128; off <<= 1) {
        int t = (tid >= off) ? s[tid - off] : 0;
        __syncthreads();
        s[tid] += t;
        __syncthreads();
    }
    if (tid < nb) bsum[tid] = (tid == 0) ? 0 : s[tid - 1];
}

__global__ __launch_bounds__(SCAN_B) void scan3_k(
    const int* __restrict__ deg_i, const int* __restrict__ deg_u,
    const int* __restrict__ part_i, const int* __restrict__ part_u,
    const int* __restrict__ bsum_i, const int* __restrict__ bsum_u,
    int* __restrict__ rowptr_i, int* __restrict__ rowptr_u,
    int* __restrict__ bcur_i, int* __restrict__ bcur_u, int nbi)
{
    const int* deg; const int* partial; const int* bsum;
    int* rowptr; int* bcur; int n, bb, sh;
    if ((int)blockIdx.x < nbi) {
        deg = deg_i; partial = part_i; bsum = bsum_i;
        rowptr = rowptr_i; bcur = bcur_i; n = NITM; bb = blockIdx.x; sh = 9;
    } else {
        deg = deg_u; partial = part_u; bsum = bsum_u;
        rowptr = rowptr_u; bcur = bcur_u; n = NUSR; bb = blockIdx.x - nbi; sh = 10;
    }
    int i = bb * SCAN_B + threadIdx.x;
    if (i < n) {
        int rs = partial[i] - deg[i] + bsum[bb];
        rowptr[i] = rs;
        if ((i & ((1 << sh) - 1)) == 0) bcur[i >> sh] = rs;  // bucket chunk cursor
    }
    if (i == 0) rowptr[n] = NEDG;
}

// ---- phase 1: partition edges into dst-bucket-major packed pair lists ----------
// Per block: LDS histogram over 98 buckets/side, ONE global atomic per bucket to
// reserve a contiguous chunk, then write packed 4B pairs into the chunk
// (~42 pairs/bucket/block = 168B bursts).
__global__ __launch_bounds__(256) void part_k(
    const int* __restrict__ u_idx, const int* __restrict__ i_idx,
    int* __restrict__ bcur_i, int* __restrict__ bcur_u,
    int* __restrict__ pair_i, int* __restrict__ pair_u)
{
    __shared__ int lh_i[KI], lh_u[KU];
    __shared__ int lb_i[KI], lb_u[KU];
    int tid = threadIdx.x;
    int base = blockIdx.x * EPB;
    int u[16], it[16];
    #pragma unroll
    for (int q = 0; q < 16; q++) {
        int e = base + q * 256 + tid;
        u[q]  = (e < NEDG) ? u_idx[e] : -1;
        it[q] = (e < NEDG) ? i_idx[e] : -1;
    }
    if (tid < KI) lh_i[tid] = 0;
    if (tid >= 128 && tid < 128 + KU) lh_u[tid - 128] = 0;
    __syncthreads();
    #pragma unroll
    for (int q = 0; q < 16; q++) if (it[q] >= 0) {
        atomicAdd(&lh_i[it[q] >> 9], 1);
        atomicAdd(&lh_u[u[q] >> 10], 1);
    }
    __syncthreads();
    if (tid < KI) { int c = lh_i[tid]; lb_i[tid] = c ? atomicAdd(&bcur_i[tid], c) : 0; }
    if (tid >= 128 && tid < 128 + KU) {
        int k = tid - 128; int c = lh_u[k];
        lb_u[k] = c ? atomicAdd(&bcur_u[k], c) : 0;
    }
    __syncthreads();
    #pragma unroll
    for (int q = 0; q < 16; q++) if (it[q] >= 0) {
        int pi_ = atomicAdd(&lb_i[it[q] >> 9], 1);
        pair_i[pi_] = ((it[q] & 511) << 17) | u[q];
        int pu_ = atomicAdd(&lb_u[u[q] >> 10], 1);
        pair_u[pu_] = ((u[q] & 1023) << 16) | it[q];
    }
}

// ---- phase 2: one block per bucket, LDS cursors (NO global atomics) ------------
// Block loads its rowptr slice into LDS, walks the bucket's contiguous pair
// range, LDS-atomicAdd for position, writes csr within the bucket's <=80KB
// region (lines fill in one XCD's L2). Idempotent across replays.
__global__ __launch_bounds__(1024) void bscat_k(
    const int* __restrict__ pair_i, const int* __restrict__ pair_u,
    const int* __restrict__ rowptr_i, const int* __restrict__ rowptr_u,
    int* __restrict__ csr_i, int* __restrict__ csr_u)
{
    __shared__ int cur[1024];
    int b = blockIdx.x;
    const int* pair; const int* rowptr; int* csr;
    int base_row, wrows, n, shsrc;
    if (b < KI) {
        pair = pair_i; rowptr = rowptr_i; csr = csr_i;
        base_row = b << 9; wrows = 512; n = NITM; shsrc = 17;
    } else {
        int k = b - KI;
        pair = pair_u; rowptr = rowptr_u; csr = csr_u;
        base_row = k << 10; wrows = 1024; n = NUSR; shsrc = 16;
    }
    int nrows = min(wrows, n - base_row);
    int t = threadIdx.x;
    if (t < nrows) cur[t] = rowptr[base_row + t];
    __syncthreads();
    int bstart = rowptr[base_row];
    int bend = rowptr[min(base_row + wrows, n)];
    int srcmask = (1 << shsrc) - 1;
    for (int e = bstart + t; e < bend; e += 1024) {
        int v = pair[e];
        int pos = atomicAdd(&cur[v >> shsrc], 1);
        csr[pos] = v & srcmask;
    }
}

// ========== layer-0 messages for both sides: msg = half(relu(x)+eps) =============
__global__ __launch_bounds__(256) void msg0_k(
    const float* __restrict__ xu, const float* __restrict__ xi,
    __half* __restrict__ msg_u, __half* __restrict__ msg_i)
{
    int i = blockIdx.x * 256 + threadIdx.x;
    const float* x; __half* msg; int idx;
    if (i < NUSR * 16) { x = xu; msg = msg_u; idx = i; }
    else { int j = i - NUSR * 16; if (j >= NITM * 16) return; x = xi; msg = msg_i; idx = j; }
    float4 v = ((const float4*)x)[idx];
    __half2 a = __floats2half2_rn(fmaxf(v.x, 0.f) + MSG_EPS, fmaxf(v.y, 0.f) + MSG_EPS);
    __half2 b = __floats2half2_rn(fmaxf(v.z, 0.f) + MSG_EPS, fmaxf(v.w, 0.f) + MSG_EPS);
    ((__half2*)msg)[idx * 2]     = a;
    ((__half2*)msg)[idx * 2 + 1] = b;
}

// ========== weight convert+transpose to fp16 (once per call) =====================
__global__ __launch_bounds__(256) void wconv_k(
    const float* __restrict__ W1, const float* __restrict__ W2,
    __half* __restrict__ W1t, __half* __restrict__ W2t)
{
    int idx = blockIdx.x * 256 + threadIdx.x;
    if (idx >= 6 * 8192) return;
    int m = idx >> 13, rem = idx & 8191;
    {   // W1 [64][128] -> [128][64]
        int k = rem >> 7, c = rem & 127;
        W1t[m * 8192 + c * 64 + k] = __float2half(W1[idx]);
    }
    {   // W2 [128][64] -> [64][128]
        int k = rem >> 6, c = rem & 63;
        W2t[m * 8192 + c * 128 + k] = __float2half(W2[idx]);
    }
}

// ===== FUSED (item-conv + user-conv) agg + GEMM1 (MFMA fp16) =====================
// no-max softmax (m in [eps,~6], exp safe): den=sum exp, num=sum exp*m, agg=num/den.
// Gather: round-8 form (per-row sequential, unroll-4 = 4 loads in flight).
// R9's 8-deep row-pairing REGRESSED (731->774us, pathological scheduling) — keep this.
// R11: B-fragments read directly from global W1t (16KB, L2-resident, identical for
// all blocks) — LDS 31.7->13.2KB lifts occupancy 5->8 blocks/CU (was latency-bound
// at Occ 41%, VALU 36%, HBM 21%).
#define UPD(u) { float2 va=__half22float2(*(__half2*)&(u).x); \
                 float2 vb=__half22float2(*(__half2*)&(u).y); \
                 float eA=__expf(va.x), eB=__expf(va.y); \
                 float eC=__expf(vb.x), eD=__expf(vb.y); \
                 dA+=eA; nA=fmaf(eA,va.x,nA); dB+=eB; nB=fmaf(eB,va.y,nB); \
                 dC+=eC; nC=fmaf(eC,vb.x,nC); dD+=eD; nD=fmaf(eD,vb.y,nD); }

__global__ __launch_bounds__(256) void aggemm1f_k(
    const __half* __restrict__ msg_i_src, const __half* __restrict__ msg_u_src,
    const float* __restrict__ xi_cur, const float* __restrict__ xu_cur,
    const int* __restrict__ rowptr_i, const int* __restrict__ rowptr_u,
    const int* __restrict__ csr_i, const int* __restrict__ csr_u,
    const __half* __restrict__ W1t_l,   // layer base: [2][128][64] f16
    const float* __restrict__ b1_l,     // [2][128]
    __half* __restrict__ h1_i, __half* __restrict__ h1_u,   // fp16 h1
    double* __restrict__ gs_l,          // [2][256] (gsum|gsq per conv)
    int gI)
{
    __shared__ _Float16 sA[64][72];      // 9.2 KB
    __shared__ float sredS[4][128];      // 2 KB
    __shared__ float sredQ[4][128];      // 2 KB

    int side = ((int)blockIdx.x < gI) ? 0 : 1;
    int bb = side ? (blockIdx.x - gI) : blockIdx.x;
    const __half* msg = side ? msg_i_src : msg_u_src;
    const float* xdst = side ? xu_cur : xi_cur;
    const int* rowptr = side ? rowptr_u : rowptr_i;
    const int* csr    = side ? csr_u : csr_i;
    const __half* W1t = W1t_l + (size_t)side * 8192;
    const float* b1   = b1_l + side * DD2;
    __half* h1        = side ? h1_u : h1_i;
    double* gsum      = gs_l + side * 256;
    double* gsq       = gsum + 128;
    int N             = side ? NUSR : NITM;

    int t = threadIdx.x;
    int r0 = bb * 64;
    int w = t >> 6, lane = t & 63, q = lane >> 4, ln = lane & 15;
    const uint2* mp = (const uint2*)msg;

    // gather + softmax-agg for this block's 64 rows, results into sA
    #pragma unroll
    for (int ii = 0; ii < 4; ii++) {
        int rr = w * 16 + ii * 4 + q;
        int r = r0 + rr;
        uint2 o = make_uint2(0u, 0u);
        if (r < N) {
            int beg = rowptr[r], end = rowptr[r + 1];
            float dA=0.f,dB=0.f,dC=0.f,dD=0.f,nA=0.f,nB=0.f,nC=0.f,nD=0.f;
            int j = beg;
            for (; j + 4 <= end; j += 4) {
                int s0=csr[j], s1=csr[j+1], s2=csr[j+2], s3=csr[j+3];
                uint2 u0 = mp[(size_t)s0*16+ln];
                uint2 u1 = mp[(size_t)s1*16+ln];
                uint2 u2 = mp[(size_t)s2*16+ln];
                uint2 u3 = mp[(size_t)s3*16+ln];
                UPD(u0) UPD(u1) UPD(u2) UPD(u3)
            }
            for (; j < end; j++) {
                uint2 u = mp[(size_t)csr[j]*16+ln];
                UPD(u)
            }
            bool nz = end > beg;
            float aA = nz ? nA/dA : 0.f;
            float aB = nz ? nB/dB : 0.f;
            float aC = nz ? nC/dC : 0.f;
            float aD = nz ? nD/dD : 0.f;
            float4 xd = ((const float4*)xdst)[(size_t)r*16 + ln];
            __half2 h01 = __floats2half2_rn(aA+xd.x, aB+xd.y);
            __half2 h23 = __floats2half2_rn(aC+xd.z, aD+xd.w);
            o.x = *(unsigned int*)&h01; o.y = *(unsigned int*)&h23;
        }
        *(uint2*)&sA[rr][ln * 4] = o;
    }
    __syncthreads();

    f16x8 afr[4][2], bfr[2][2];
    #pragma unroll
    for (int rt = 0; rt < 4; rt++)
        #pragma unroll
        for (int ks = 0; ks < 2; ks++)
            afr[rt][ks] = *(const f16x8*)&sA[rt * 16 + ln][ks * 32 + q * 8];
    const f16x8* Wv = (const f16x8*)W1t;   // [row 0..127][k-frag]: idx = row*8 + ks*4 + q
    #pragma unroll
    for (int ct = 0; ct < 2; ct++)
        #pragma unroll
        for (int ks = 0; ks < 2; ks++)
            bfr[ct][ks] = Wv[(w * 32 + ct * 16 + ln) * 8 + ks * 4 + q];

    f32x4 acc[4][2];
    #pragma unroll
    for (int rt = 0; rt < 4; rt++)
        #pragma unroll
        for (int ct = 0; ct < 2; ct++)
            acc[rt][ct] = (f32x4){0.f, 0.f, 0.f, 0.f};

    #pragma unroll
    for (int rt = 0; rt < 4; rt++)
        #pragma unroll
        for (int ct = 0; ct < 2; ct++) {
            acc[rt][ct] = __builtin_amdgcn_mfma_f32_16x16x32_f16(
                afr[rt][0], bfr[ct][0], acc[rt][ct], 0, 0, 0);
            acc[rt][ct] = __builtin_amdgcn_mfma_f32_16x16x32_f16(
                afr[rt][1], bfr[ct][1], acc[rt][ct], 0, 0, 0);
        }

    float b1c0 = b1[w * 32 + ln];
    float b1c1 = b1[w * 32 + 16 + ln];
    float ps0 = 0.f, pq0 = 0.f, ps1 = 0.f, pq1 = 0.f;
    #pragma unroll
    for (int rt = 0; rt < 4; rt++) {
        #pragma unroll
        for (int i = 0; i < 4; i++) {
            int r = r0 + rt * 16 + q * 4 + i;
            if (r < N) {
                float h0 = acc[rt][0][i] + b1c0;
                float h1v = acc[rt][1][i] + b1c1;
                h1[(size_t)r * DD2 + w * 32 + ln] = __float2half(h0);
                h1[(size_t)r * DD2 + w * 32 + 16 + ln] = __float2half(h1v);
                ps0 += h0; pq0 += h0 * h0;
                ps1 += h1v; pq1 += h1v * h1v;
            }
        }
    }
    sredS[q][w * 32 + ln] = ps0;  sredS[q][w * 32 + 16 + ln] = ps1;
    sredQ[q][w * 32 + ln] = pq0;  sredQ[q][w * 32 + 16 + ln] = pq1;
    __syncthreads();
    if (t < 128) {
        float s = 0.f, qq = 0.f;
        #pragma unroll
        for (int k = 0; k < 4; k++) { s += sredS[k][t]; qq += sredQ[k][t]; }
        atomicAdd(&gsum[t], (double)s);
        atomicAdd(&gsq[t],  (double)qq);
    }
}

// ===== FUSED GEMM2 (both convs): xnew = relu(relu(bn(h1)) @ W2 + b2) + msgs ======
// R11: W2t B-fragments read directly from global (16KB L2-resident) — LDS
// 35.8->18.4KB lifts occupancy 4->8 blocks/CU.
__global__ __launch_bounds__(256) void gemm2f_k(
    const __half* __restrict__ h1_i, const __half* __restrict__ h1_u,
    const double* __restrict__ gs_l,
    const float* __restrict__ gamma_l, const float* __restrict__ beta_l,
    const __half* __restrict__ W2t_l, const float* __restrict__ b2_l,
    float* __restrict__ xi_new, float* __restrict__ xu_new,
    __half* __restrict__ msgi_out, __half* __restrict__ msgu_out, int gI)
{
    __shared__ _Float16 sA[64][136];    // 17.4 KB
    __shared__ float2 sss[DD2];         // 1 KB

    int side = ((int)blockIdx.x < gI) ? 0 : 1;
    int bb = side ? (blockIdx.x - gI) : blockIdx.x;
    const __half* h1   = side ? h1_u : h1_i;
    const double* gsum = gs_l + side * 256;
    const double* gsq  = gsum + 128;
    const float* gamma = gamma_l + side * DD2;
    const float* beta  = beta_l + side * DD2;
    const __half* W2t  = W2t_l + (size_t)side * 8192;
    const float* b2    = b2_l + side * DD;
    float* xnew        = side ? xu_new : xi_new;
    __half* msgout     = side ? msgu_out : msgi_out;
    int N              = side ? NUSR : NITM;

    int t = threadIdx.x;
    if (t < 128) {
        double mean = gsum[t] / (double)N;
        double var  = gsq[t] / (double)N - mean * mean;
        float inv = (float)(1.0 / sqrt(var + (double)BN_EPS));
        float sc = gamma[t] * inv;
        sss[t] = make_float2(sc, beta[t] - (float)mean * sc);
    }
    __syncthreads();

    int r0 = bb * 64;
    // stage h1 (fp16) with BN + relu -> fp16: 64 rows x 32 uint2 (4 halves each)
    for (int i = t; i < 2048; i += 256) {
        int rr = i >> 5, c4 = i & 31;
        int r = r0 + rr;
        uint2 o = make_uint2(0u, 0u);
        if (r < N) {
            uint2 hv = ((const uint2*)h1)[(size_t)r * 32 + c4];
            float2 va = __half22float2(*(__half2*)&hv.x);
            float2 vb = __half22float2(*(__half2*)&hv.y);
            float2 s0 = sss[c4 * 4], s1 = sss[c4 * 4 + 1];
            float2 s2 = sss[c4 * 4 + 2], s3 = sss[c4 * 4 + 3];
            va.x = fmaxf(fmaf(va.x, s0.x, s0.y), 0.f);
            va.y = fmaxf(fmaf(va.y, s1.x, s1.y), 0.f);
            vb.x = fmaxf(fmaf(vb.x, s2.x, s2.y), 0.f);
            vb.y = fmaxf(fmaf(vb.y, s3.x, s3.y), 0.f);
            __half2 a = __floats2half2_rn(va.x, va.y);
            __half2 b = __floats2half2_rn(vb.x, vb.y);
            o.x = *(unsigned int*)&a; o.y = *(unsigned int*)&b;
        }
        *(uint2*)&sA[rr][c4 * 4] = o;
    }
    __syncthreads();

    int w = t >> 6, lane = t & 63, q = lane >> 4, ln = lane & 15;
    f32x4 acc[4];
    #pragma unroll
    for (int rt = 0; rt < 4; rt++) acc[rt] = (f32x4){0.f, 0.f, 0.f, 0.f};

    const f16x8* Wv = (const f16x8*)W2t;   // [row 0..63][k-frag]: idx = row*16 + ks*4 + q
    #pragma unroll
    for (int ks = 0; ks < 4; ks++) {
        f16x8 bf = Wv[(w * 16 + ln) * 16 + ks * 4 + q];
        #pragma unroll
        for (int rt = 0; rt < 4; rt++) {
            f16x8 af = *(const f16x8*)&sA[rt * 16 + ln][ks * 32 + q * 8];
            acc[rt] = __builtin_amdgcn_mfma_f32_16x16x32_f16(af, bf, acc[rt], 0, 0, 0);
        }
    }

    int c = w * 16 + ln;
    float bb2 = b2[c];
    #pragma unroll
    for (int rt = 0; rt < 4; rt++) {
        #pragma unroll
        for (int i = 0; i < 4; i++) {
            int r = r0 + rt * 16 + q * 4 + i;
            if (r < N) {
                float o = fmaxf(acc[rt][i] + bb2, 0.f);
                xnew[(size_t)r * DD + c] = o;
                msgout[(size_t)r * DD + c] = __float2half(o + MSG_EPS);
            }
        }
    }
}

// ================= decoder ========================================================
__global__ __launch_bounds__(256) void decode_k(
    const float* __restrict__ xu, const float* __restrict__ xi,
    const int* __restrict__ pu, const int* __restrict__ pi,
    float* __restrict__ out)
{
    int idx = blockIdx.x * 256 + threadIdx.x;
    int b = idx >> 4, lane = idx & 15;
    if (b >= NPRED) return;
    int u = pu[b], it = pi[b];
    float4 a = ((const float4*)(xu + (size_t)u * DD))[lane];
    float4 c = ((const float4*)(xi + (size_t)it * DD))[lane];
    float s = a.x * c.x + a.y * c.y + a.z * c.z + a.w * c.w;
    #pragma unroll
    for (int off = 8; off; off >>= 1) s += __shfl_down(s, off, 16);
    if (lane == 0) out[b] = s;
}

extern "C" void kernel_launch(void* const* d_in, const int* in_sizes, int n_in,
                              void* d_out, int out_size, void* d_ws, size_t ws_size,
                              hipStream_t stream)
{
    const float* x_user = (const float*)d_in[0];
    const float* x_item = (const float*)d_in[1];
    const float* W1    = (const float*)d_in[2];   // [3][2][64][128]
    const float* b1    = (const float*)d_in[3];
    const float* gamma = (const float*)d_in[4];
    const float* beta  = (const float*)d_in[5];
    const float* W2    = (const float*)d_in[6];   // [3][2][128][64]
    const float* b2    = (const float*)d_in[7];
    const int* edge = (const int*)d_in[8];        // [2][E]
    const int* pred = (const int*)d_in[9];        // [2][B]
    float* out = (float*)d_out;

    const int* u_idx = edge;
    const int* i_idx = edge + NEDG;

    // ---- workspace bump allocator (256B aligned chunks) ----
    char* p = (char*)d_ws;
    #define ALLOC(ptr, type, count) \
        type* ptr = (type*)p; p += (((size_t)(count) * sizeof(type)) + 255) & ~(size_t)255;

    ALLOC(deg_i, int, NITM)
    ALLOC(deg_u, int, NUSR)
    ALLOC(gsumAll, double, 12 * 256)             // 6 convs x (gsum[128]|gsq[128])
    size_t zero_span = (char*)p - (char*)deg_i;
    ALLOC(part_i, int, NITM)
    ALLOC(part_u, int, NUSR)
    ALLOC(bsum_i, int, 128)
    ALLOC(bsum_u, int, 128)
    ALLOC(bcur_i, int, 128)
    ALLOC(bcur_u, int, 128)
    ALLOC(rowptr_i, int, NITM + 1)
    ALLOC(rowptr_u, int, NUSR + 1)
    ALLOC(csr_i, int, NEDG)
    ALLOC(csr_u, int, NEDG)
    ALLOC(h1_i, __half, (size_t)NITM * DD2)
    ALLOC(h1_u, __half, (size_t)NUSR * DD2)
    ALLOC(W1t, __half, 6 * 8192)
    ALLOC(W2t, __half, 6 * 8192)
    ALLOC(xu0, float, (size_t)NUSR * DD)
    ALLOC(xu1, float, (size_t)NUSR * DD)
    ALLOC(xi0, float, (size_t)NITM * DD)
    ALLOC(xi1, float, (size_t)NITM * DD)
    ALLOC(msg_u, __half, (size_t)NUSR * DD)
    ALLOC(msg_i0, __half, (size_t)NITM * DD)
    ALLOC(msg_i1, __half, (size_t)NITM * DD)
    #undef ALLOC
    float* xu_buf[2] = {xu0, xu1};
    float* xi_buf[2] = {xi0, xi1};

    // packed pair lists (phase-1 output) alias h1 buffers: pairs are consumed by
    // bscat_k strictly BEFORE aggemm1f_k first writes h1 (same stream).
    // pair_i needs 4MB <= h1_i's 12.8MB; pair_u 4MB <= h1_u's 25.6MB.
    int* pair_i = (int*)h1_i;
    int* pair_u = (int*)h1_u;

    // ---- CSR build + converts (once; reused by all 3 layers) ----
    hipMemsetAsync(deg_i, 0, zero_span, stream);
    int eb4 = (NEDG / 4 + 255) / 256;
    count_k<<<eb4, 256, 0, stream>>>(u_idx, i_idx, deg_u, deg_i);

    int nbi = (NITM + SCAN_B - 1) / SCAN_B;   // 49
    int nbu = (NUSR + SCAN_B - 1) / SCAN_B;   // 98
    scan1_k<<<nbi + nbu, SCAN_B, 0, stream>>>(deg_i, deg_u, part_i, part_u,
                                              bsum_i, bsum_u, nbi);
    scan2_k<<<2, 128, 0, stream>>>(bsum_i, bsum_u, nbi, nbu);
    scan3_k<<<nbi + nbu, SCAN_B, 0, stream>>>(deg_i, deg_u, part_i, part_u,
                                              bsum_i, bsum_u, rowptr_i, rowptr_u,
                                              bcur_i, bcur_u, nbi);
    int pb = (NEDG + EPB - 1) / EPB;          // 245
    part_k<<<pb, 256, 0, stream>>>(u_idx, i_idx, bcur_i, bcur_u, pair_i, pair_u);
    bscat_k<<<KI + KU, 1024, 0, stream>>>(pair_i, pair_u, rowptr_i, rowptr_u,
                                          csr_i, csr_u);

    wconv_k<<<(6 * 8192 + 255) / 256, 256, 0, stream>>>(W1, W2, W1t, W2t);
    msg0_k<<<((NUSR + NITM) * 16 + 255) / 256, 256, 0, stream>>>(x_user, x_item,
                                                                 msg_u, msg_i0);

    // ---- 3 layers, each = 1 fused aggemm1 + 1 fused gemm2 ----
    int gI = (NITM + 63) / 64;    // 782 item blocks
    int gU = (NUSR + 63) / 64;    // 1563 user blocks
    const float* cu = x_user;
    const float* ci = x_item;
    __half* msgi = msg_i0;
    __half* msgi_alt = msg_i1;
    for (int l = 0; l < 3; l++) {
        float* ni = xi_buf[l & 1];
        float* nu = xu_buf[l & 1];
        aggemm1f_k<<<gI + gU, 256, 0, stream>>>(
            msgi, msg_u, ci, cu, rowptr_i, rowptr_u, csr_i, csr_u,
            W1t + (size_t)l * 2 * 8192, b1 + (size_t)l * 2 * DD2,
            h1_i, h1_u, gsumAll + l * 2 * 256, gI);
        gemm2f_k<<<gI + gU, 256, 0, stream>>>(
            h1_i, h1_u, gsumAll + l * 2 * 256,
            gamma + (size_t)l * 2 * DD2, beta + (size_t)l * 2 * DD2,
            W2t + (size_t)l * 2 * 8192, b2 + (size_t)l * 2 * DD,
            ni, nu, msgi_alt, msg_u, gI);
        cu = nu; ci = ni;
        __half* tmp = msgi; msgi = msgi_alt; msgi_alt = tmp;
    }

    decode_k<<<(NPRED * 16) / 256, 256, 0, stream>>>(cu, ci, pred, pred + NPRED, out);
}

// Round 3
// 568.716 us; speedup vs baseline: 1.2246x; 1.0959x over previous
//
#include <hip/hip_runtime.h>
#include <hip/hip_fp16.h>

#define NUSR 100000
#define NITM 50000
#define NEDG 1000000
#define NPRED 250000
#define DD 64
#define DD2 128
#define MSG_EPS 1e-7f
#define BN_EPS 1e-5f
#define SCAN_B 1024

// CSR-build bucketing: items W=512 (shift 9), users W=1024 (shift 10) -> 98 buckets each.
// Pair packing (27 bits): items (dstoff<<17)|src_user; users (dstoff<<16)|src_item.
#define KI 98
#define KU 98
#define EPB 4096   // edges per part_k block
#define ICAP 1536  // LDS-staged csr entries per aggemm1 block (mean 1280, sd 36 for
                   // item blocks; overflow falls back to global path, still correct)

typedef _Float16 f16x8 __attribute__((ext_vector_type(8)));
typedef float f32x4 __attribute__((ext_vector_type(4)));

// ================= CSR build (once per call; edges are layer-invariant) ==========
// R10: 2-level scatter replaced atomic scatter_k (134MB partial-line WB, 136us).
// R11: phase-2 global atomics removed: per-bucket block with LDS cursors, packed
// 4B pairs. Idempotent.

__global__ __launch_bounds__(256) void count_k(
    const int* __restrict__ u_idx, const int* __restrict__ i_idx,
    int* __restrict__ deg_u, int* __restrict__ deg_i)
{
    int base = (blockIdx.x * 256 + threadIdx.x) * 4;
    int u[4], it[4];
    #pragma unroll
    for (int q = 0; q < 4; q++) {
        int e = base + q;
        u[q]  = (e < NEDG) ? u_idx[e] : -1;
        it[q] = (e < NEDG) ? i_idx[e] : -1;
    }
    #pragma unroll
    for (int q = 0; q < 4; q++) if (it[q] >= 0) atomicAdd(&deg_i[it[q]], 1);
    #pragma unroll
    for (int q = 0; q < 4; q++) if (u[q] >= 0) atomicAdd(&deg_u[u[q]], 1);
}

__global__ __launch_bounds__(SCAN_B) void scan1_k(
    const int* __restrict__ deg_i, const int* __restrict__ deg_u,
    int* __restrict__ part_i, int* __restrict__ part_u,
    int* __restrict__ bsum_i, int* __restrict__ bsum_u, int nbi)
{
    __shared__ int s[SCAN_B];
    const int* deg; int* partial; int* bsum; int n, bb;
    if ((int)blockIdx.x < nbi) { deg = deg_i; partial = part_i; bsum = bsum_i; n = NITM; bb = blockIdx.x; }
    else { deg = deg_u; partial = part_u; bsum = bsum_u; n = NUSR; bb = blockIdx.x - nbi; }
    int tid = threadIdx.x;
    int i = bb * SCAN_B + tid;
    s[tid] = (i < n) ? deg[i] : 0;
    __syncthreads();
    for (int off = 1; off < SCAN_B; off <<= 1) {
        int t = (tid >= off) ? s[tid - off] : 0;
        __syncthreads();
        s[tid] += t;
        __syncthreads();
    }
    if (i < n) partial[i] = s[tid];
    if (tid == SCAN_B - 1) bsum[bb] = s[tid];
}

__global__ __launch_bounds__(128) void scan2_k(
    int* __restrict__ bsum_i, int* __restrict__ bsum_u, int nbi, int nbu)
{
    __shared__ int s[128];
    int* bsum = (blockIdx.x == 0) ? bsum_i : bsum_u;
    int nb = (blockIdx.x == 0) ? nbi : nbu;
    int tid = threadIdx.x;
    s[tid] = (tid < nb) ? bsum[tid] : 0;
    __syncthreads();
    for (int off = 1; off < 128; off <<= 1) {
        int t = (tid >= off) ? s[tid - off] : 0;
        __syncthreads();
        s[tid] += t;
        __syncthreads();
    }
    if (tid < nb) bsum[tid] = (tid == 0) ? 0 : s[tid - 1];
}

__global__ __launch_bounds__(SCAN_B) void scan3_k(
    const int* __restrict__ deg_i, const int* __restrict__ deg_u,
    const int* __restrict__ part_i, const int* __restrict__ part_u,
    const int* __restrict__ bsum_i, const int* __restrict__ bsum_u,
    int* __restrict__ rowptr_i, int* __restrict__ rowptr_u,
    int* __restrict__ bcur_i, int* __restrict__ bcur_u, int nbi)
{
    const int* deg; const int* partial; const int* bsum;
    int* rowptr; int* bcur; int n, bb, sh;
    if ((int)blockIdx.x < nbi) {
        deg = deg_i; partial = part_i; bsum = bsum_i;
        rowptr = rowptr_i; bcur = bcur_i; n = NITM; bb = blockIdx.x; sh = 9;
    } else {
        deg = deg_u; partial = part_u; bsum = bsum_u;
        rowptr = rowptr_u; bcur = bcur_u; n = NUSR; bb = blockIdx.x - nbi; sh = 10;
    }
    int i = bb * SCAN_B + threadIdx.x;
    if (i < n) {
        int rs = partial[i] - deg[i] + bsum[bb];
        rowptr[i] = rs;
        if ((i & ((1 << sh) - 1)) == 0) bcur[i >> sh] = rs;  // bucket chunk cursor
    }
    if (i == 0) rowptr[n] = NEDG;
}

// ---- phase 1: partition edges into dst-bucket-major packed pair lists ----------
__global__ __launch_bounds__(256) void part_k(
    const int* __restrict__ u_idx, const int* __restrict__ i_idx,
    int* __restrict__ bcur_i, int* __restrict__ bcur_u,
    int* __restrict__ pair_i, int* __restrict__ pair_u)
{
    __shared__ int lh_i[KI], lh_u[KU];
    __shared__ int lb_i[KI], lb_u[KU];
    int tid = threadIdx.x;
    int base = blockIdx.x * EPB;
    int u[16], it[16];
    #pragma unroll
    for (int q = 0; q < 16; q++) {
        int e = base + q * 256 + tid;
        u[q]  = (e < NEDG) ? u_idx[e] : -1;
        it[q] = (e < NEDG) ? i_idx[e] : -1;
    }
    if (tid < KI) lh_i[tid] = 0;
    if (tid >= 128 && tid < 128 + KU) lh_u[tid - 128] = 0;
    __syncthreads();
    #pragma unroll
    for (int q = 0; q < 16; q++) if (it[q] >= 0) {
        atomicAdd(&lh_i[it[q] >> 9], 1);
        atomicAdd(&lh_u[u[q] >> 10], 1);
    }
    __syncthreads();
    if (tid < KI) { int c = lh_i[tid]; lb_i[tid] = c ? atomicAdd(&bcur_i[tid], c) : 0; }
    if (tid >= 128 && tid < 128 + KU) {
        int k = tid - 128; int c = lh_u[k];
        lb_u[k] = c ? atomicAdd(&bcur_u[k], c) : 0;
    }
    __syncthreads();
    #pragma unroll
    for (int q = 0; q < 16; q++) if (it[q] >= 0) {
        int pi_ = atomicAdd(&lb_i[it[q] >> 9], 1);
        pair_i[pi_] = ((it[q] & 511) << 17) | u[q];
        int pu_ = atomicAdd(&lb_u[u[q] >> 10], 1);
        pair_u[pu_] = ((u[q] & 1023) << 16) | it[q];
    }
}

// ---- phase 2: one block per bucket, LDS cursors (NO global atomics) ------------
__global__ __launch_bounds__(1024) void bscat_k(
    const int* __restrict__ pair_i, const int* __restrict__ pair_u,
    const int* __restrict__ rowptr_i, const int* __restrict__ rowptr_u,
    int* __restrict__ csr_i, int* __restrict__ csr_u)
{
    __shared__ int cur[1024];
    int b = blockIdx.x;
    const int* pair; const int* rowptr; int* csr;
    int base_row, wrows, n, shsrc;
    if (b < KI) {
        pair = pair_i; rowptr = rowptr_i; csr = csr_i;
        base_row = b << 9; wrows = 512; n = NITM; shsrc = 17;
    } else {
        int k = b - KI;
        pair = pair_u; rowptr = rowptr_u; csr = csr_u;
        base_row = k << 10; wrows = 1024; n = NUSR; shsrc = 16;
    }
    int nrows = min(wrows, n - base_row);
    int t = threadIdx.x;
    if (t < nrows) cur[t] = rowptr[base_row + t];
    __syncthreads();
    int bstart = rowptr[base_row];
    int bend = rowptr[min(base_row + wrows, n)];
    int srcmask = (1 << shsrc) - 1;
    for (int e = bstart + t; e < bend; e += 1024) {
        int v = pair[e];
        int pos = atomicAdd(&cur[v >> shsrc], 1);
        csr[pos] = v & srcmask;
    }
}

// ========== layer-0 messages for both sides: msg = half(relu(x)+eps) =============
__global__ __launch_bounds__(256) void msg0_k(
    const float* __restrict__ xu, const float* __restrict__ xi,
    __half* __restrict__ msg_u, __half* __restrict__ msg_i)
{
    int i = blockIdx.x * 256 + threadIdx.x;
    const float* x; __half* msg; int idx;
    if (i < NUSR * 16) { x = xu; msg = msg_u; idx = i; }
    else { int j = i - NUSR * 16; if (j >= NITM * 16) return; x = xi; msg = msg_i; idx = j; }
    float4 v = ((const float4*)x)[idx];
    __half2 a = __floats2half2_rn(fmaxf(v.x, 0.f) + MSG_EPS, fmaxf(v.y, 0.f) + MSG_EPS);
    __half2 b = __floats2half2_rn(fmaxf(v.z, 0.f) + MSG_EPS, fmaxf(v.w, 0.f) + MSG_EPS);
    ((__half2*)msg)[idx * 2]     = a;
    ((__half2*)msg)[idx * 2 + 1] = b;
}

// ========== weight convert+transpose to fp16 (once per call) =====================
__global__ __launch_bounds__(256) void wconv_k(
    const float* __restrict__ W1, const float* __restrict__ W2,
    __half* __restrict__ W1t, __half* __restrict__ W2t)
{
    int idx = blockIdx.x * 256 + threadIdx.x;
    if (idx >= 6 * 8192) return;
    int m = idx >> 13, rem = idx & 8191;
    {   // W1 [64][128] -> [128][64]
        int k = rem >> 7, c = rem & 127;
        W1t[m * 8192 + c * 64 + k] = __float2half(W1[idx]);
    }
    {   // W2 [128][64] -> [64][128]
        int k = rem >> 6, c = rem & 63;
        W2t[m * 8192 + c * 128 + k] = __float2half(W2[idx]);
    }
}

// ===== FUSED (item-conv + user-conv) agg + GEMM1 (MFMA fp16) =====================
// no-max softmax (m in [eps,~6], exp safe): den=sum exp, num=sum exp*m, agg=num/den.
// R12 gather restructure (was latency-bound: Occ 34%, VALU 34%, HBM 18%):
//  - 8-lane row groups, uint4 (16B) msg loads: 1 VMEM/edge (was 2), 8 independent
//    streams/wave (was 4), per-group chain = 2 rows (was 4).
//  - csr slice staged in LDS (coalesced, off the dependent chain); ICAP overflow
//    falls back to global path (correct, ~never taken).
//  - sA stride 88 (16B-aligned rows, <=2-way bank aliasing); idx buffer aliases
//    BN-reduce scratch (dead after pre-MFMA barrier). LDS 17.4KB -> 8 blocks/CU.
#define UPD4(U) { \
    float2 va=__half22float2(*(__half2*)&(U).x); \
    float2 vb=__half22float2(*(__half2*)&(U).y); \
    float2 vc=__half22float2(*(__half2*)&(U).z); \
    float2 vd=__half22float2(*(__half2*)&(U).w); \
    float e0=__expf(va.x), e1=__expf(va.y), e2=__expf(vb.x), e3=__expf(vb.y); \
    float e4=__expf(vc.x), e5=__expf(vc.y), e6=__expf(vd.x), e7=__expf(vd.y); \
    d0+=e0; n0=fmaf(e0,va.x,n0); d1+=e1; n1=fmaf(e1,va.y,n1); \
    d2+=e2; n2=fmaf(e2,vb.x,n2); d3+=e3; n3=fmaf(e3,vb.y,n3); \
    d4+=e4; n4=fmaf(e4,vc.x,n4); d5+=e5; n5=fmaf(e5,vc.y,n5); \
    d6+=e6; n6=fmaf(e6,vd.x,n6); d7+=e7; n7=fmaf(e7,vd.y,n7); }

#define GBODY(IDXE) { \
    int j = beg; \
    for (; j + 4 <= end; j += 4) { \
        int s0=(IDXE(j)), s1=(IDXE(j+1)), s2=(IDXE(j+2)), s3=(IDXE(j+3)); \
        uint4 u0 = mp4[s0*8+l8]; uint4 u1 = mp4[s1*8+l8]; \
        uint4 u2 = mp4[s2*8+l8]; uint4 u3 = mp4[s3*8+l8]; \
        UPD4(u0) UPD4(u1) UPD4(u2) UPD4(u3) } \
    for (; j < end; j++) { int ss=(IDXE(j)); uint4 uu = mp4[ss*8+l8]; UPD4(uu) } }

#define IDX_L(jj) su.idx[(jj)]
#define IDX_G(jj) csr[blkBeg + (jj)]

union AggSU { int idx[ICAP]; float red[8][128]; };

__global__ __launch_bounds__(256) void aggemm1f_k(
    const __half* __restrict__ msg_i_src, const __half* __restrict__ msg_u_src,
    const float* __restrict__ xi_cur, const float* __restrict__ xu_cur,
    const int* __restrict__ rowptr_i, const int* __restrict__ rowptr_u,
    const int* __restrict__ csr_i, const int* __restrict__ csr_u,
    const __half* __restrict__ W1t_l,   // layer base: [2][128][64] f16
    const float* __restrict__ b1_l,     // [2][128]
    __half* __restrict__ h1_i, __half* __restrict__ h1_u,   // fp16 h1
    double* __restrict__ gs_l,          // [2][256] (gsum|gsq per conv)
    int gI)
{
    __shared__ _Float16 sA[64][88];      // 11.3 KB, rows 16B-aligned
    __shared__ AggSU su;                 // 6 KB (idx) / 4 KB (red)

    int side = ((int)blockIdx.x < gI) ? 0 : 1;
    int bb = side ? (blockIdx.x - gI) : blockIdx.x;
    const __half* msg = side ? msg_i_src : msg_u_src;
    const float* xdst = side ? xu_cur : xi_cur;
    const int* rowptr = side ? rowptr_u : rowptr_i;
    const int* csr    = side ? csr_u : csr_i;
    const __half* W1t = W1t_l + (size_t)side * 8192;
    const float* b1   = b1_l + side * DD2;
    __half* h1        = side ? h1_u : h1_i;
    double* gsum      = gs_l + side * 256;
    double* gsq       = gsum + 128;
    int N             = side ? NUSR : NITM;

    int t = threadIdx.x;
    int r0 = bb * 64;
    int w = t >> 6, lane = t & 63;
    int g = lane >> 3, l8 = lane & 7;          // gather layout: 8 lanes/row
    int q = lane >> 4, ln = lane & 15;         // MFMA layout
    const uint4* mp4 = (const uint4*)msg;

    // ---- stage this block's csr slice (coalesced, off the dependent chain) ----
    int blkBeg = rowptr[r0];
    int blkEnd = rowptr[min(r0 + 64, N)];
    int nE = blkEnd - blkBeg;
    for (int e = t; e < nE && e < ICAP; e += 256) su.idx[e] = csr[blkBeg + e];
    __syncthreads();

    // ---- gather + softmax-agg: wave w rows [w*16, w*16+16), group g, 2 rows ----
    #pragma unroll
    for (int ii = 0; ii < 2; ii++) {
        int rr = w * 16 + ii * 8 + g;
        int r = r0 + rr;
        uint4 o = make_uint4(0u, 0u, 0u, 0u);
        if (r < N) {
            int beg = rowptr[r] - blkBeg;
            int end = rowptr[r + 1] - blkBeg;
            float d0=0.f,d1=0.f,d2=0.f,d3=0.f,d4=0.f,d5=0.f,d6=0.f,d7=0.f;
            float n0=0.f,n1=0.f,n2=0.f,n3=0.f,n4=0.f,n5=0.f,n6=0.f,n7=0.f;
            if (end <= ICAP) { GBODY(IDX_L) } else { GBODY(IDX_G) }
            bool nz = end > beg;
            float a0 = nz ? n0/d0 : 0.f, a1 = nz ? n1/d1 : 0.f;
            float a2 = nz ? n2/d2 : 0.f, a3 = nz ? n3/d3 : 0.f;
            float a4 = nz ? n4/d4 : 0.f, a5 = nz ? n5/d5 : 0.f;
            float a6 = nz ? n6/d6 : 0.f, a7 = nz ? n7/d7 : 0.f;
            const float4* xr = (const float4*)xdst + (size_t)r * 16;
            float4 x0 = xr[l8 * 2], x1 = xr[l8 * 2 + 1];
            __half2 p0 = __floats2half2_rn(a0 + x0.x, a1 + x0.y);
            __half2 p1 = __floats2half2_rn(a2 + x0.z, a3 + x0.w);
            __half2 p2 = __floats2half2_rn(a4 + x1.x, a5 + x1.y);
            __half2 p3 = __floats2half2_rn(a6 + x1.z, a7 + x1.w);
            o.x = *(unsigned int*)&p0; o.y = *(unsigned int*)&p1;
            o.z = *(unsigned int*)&p2; o.w = *(unsigned int*)&p3;
        }
        *(uint4*)&sA[rr][l8 * 8] = o;
    }
    __syncthreads();

    f16x8 afr[4][2], bfr[2][2];
    #pragma unroll
    for (int rt = 0; rt < 4; rt++)
        #pragma unroll
        for (int ks = 0; ks < 2; ks++)
            afr[rt][ks] = *(const f16x8*)&sA[rt * 16 + ln][ks * 32 + q * 8];
    const f16x8* Wv = (const f16x8*)W1t;   // [row 0..127][k-frag]: idx = row*8 + ks*4 + q
    #pragma unroll
    for (int ct = 0; ct < 2; ct++)
        #pragma unroll
        for (int ks = 0; ks < 2; ks++)
            bfr[ct][ks] = Wv[(w * 32 + ct * 16 + ln) * 8 + ks * 4 + q];

    f32x4 acc[4][2];
    #pragma unroll
    for (int rt = 0; rt < 4; rt++)
        #pragma unroll
        for (int ct = 0; ct < 2; ct++)
            acc[rt][ct] = (f32x4){0.f, 0.f, 0.f, 0.f};

    #pragma unroll
    for (int rt = 0; rt < 4; rt++)
        #pragma unroll
        for (int ct = 0; ct < 2; ct++) {
            acc[rt][ct] = __builtin_amdgcn_mfma_f32_16x16x32_f16(
                afr[rt][0], bfr[ct][0], acc[rt][ct], 0, 0, 0);
            acc[rt][ct] = __builtin_amdgcn_mfma_f32_16x16x32_f16(
                afr[rt][1], bfr[ct][1], acc[rt][ct], 0, 0, 0);
        }

    float b1c0 = b1[w * 32 + ln];
    float b1c1 = b1[w * 32 + 16 + ln];
    float ps0 = 0.f, pq0 = 0.f, ps1 = 0.f, pq1 = 0.f;
    #pragma unroll
    for (int rt = 0; rt < 4; rt++) {
        #pragma unroll
        for (int i = 0; i < 4; i++) {
            int r = r0 + rt * 16 + q * 4 + i;
            if (r < N) {
                float h0 = acc[rt][0][i] + b1c0;
                float h1v = acc[rt][1][i] + b1c1;
                h1[(size_t)r * DD2 + w * 32 + ln] = __float2half(h0);
                h1[(size_t)r * DD2 + w * 32 + 16 + ln] = __float2half(h1v);
                ps0 += h0; pq0 += h0 * h0;
                ps1 += h1v; pq1 += h1v * h1v;
            }
        }
    }
    // su.idx is dead (last read before the pre-MFMA barrier) -> reuse as red scratch
    su.red[q][w * 32 + ln] = ps0;      su.red[q][w * 32 + 16 + ln] = ps1;
    su.red[4 + q][w * 32 + ln] = pq0;  su.red[4 + q][w * 32 + 16 + ln] = pq1;
    __syncthreads();
    if (t < 128) {
        float s = 0.f, qq = 0.f;
        #pragma unroll
        for (int k = 0; k < 4; k++) { s += su.red[k][t]; qq += su.red[4 + k][t]; }
        atomicAdd(&gsum[t], (double)s);
        atomicAdd(&gsq[t],  (double)qq);
    }
}

// ===== FUSED GEMM2 (both convs): xnew = relu(relu(bn(h1)) @ W2 + b2) + msgs ======
__global__ __launch_bounds__(256) void gemm2f_k(
    const __half* __restrict__ h1_i, const __half* __restrict__ h1_u,
    const double* __restrict__ gs_l,
    const float* __restrict__ gamma_l, const float* __restrict__ beta_l,
    const __half* __restrict__ W2t_l, const float* __restrict__ b2_l,
    float* __restrict__ xi_new, float* __restrict__ xu_new,
    __half* __restrict__ msgi_out, __half* __restrict__ msgu_out, int gI)
{
    __shared__ _Float16 sA[64][136];    // 17.4 KB
    __shared__ float2 sss[DD2];         // 1 KB

    int side = ((int)blockIdx.x < gI) ? 0 : 1;
    int bb = side ? (blockIdx.x - gI) : blockIdx.x;
    const __half* h1   = side ? h1_u : h1_i;
    const double* gsum = gs_l + side * 256;
    const double* gsq  = gsum + 128;
    const float* gamma = gamma_l + side * DD2;
    const float* beta  = beta_l + side * DD2;
    const __half* W2t  = W2t_l + (size_t)side * 8192;
    const float* b2    = b2_l + side * DD;
    float* xnew        = side ? xu_new : xi_new;
    __half* msgout     = side ? msgu_out : msgi_out;
    int N              = side ? NUSR : NITM;

    int t = threadIdx.x;
    if (t < 128) {
        double mean = gsum[t] / (double)N;
        double var  = gsq[t] / (double)N - mean * mean;
        float inv = (float)(1.0 / sqrt(var + (double)BN_EPS));
        float sc = gamma[t] * inv;
        sss[t] = make_float2(sc, beta[t] - (float)mean * sc);
    }
    __syncthreads();

    int r0 = bb * 64;
    // stage h1 (fp16) with BN + relu -> fp16: 64 rows x 32 uint2 (4 halves each)
    for (int i = t; i < 2048; i += 256) {
        int rr = i >> 5, c4 = i & 31;
        int r = r0 + rr;
        uint2 o = make_uint2(0u, 0u);
        if (r < N) {
            uint2 hv = ((const uint2*)h1)[(size_t)r * 32 + c4];
            float2 va = __half22float2(*(__half2*)&hv.x);
            float2 vb = __half22float2(*(__half2*)&hv.y);
            float2 s0 = sss[c4 * 4], s1 = sss[c4 * 4 + 1];
            float2 s2 = sss[c4 * 4 + 2], s3 = sss[c4 * 4 + 3];
            va.x = fmaxf(fmaf(va.x, s0.x, s0.y), 0.f);
            va.y = fmaxf(fmaf(va.y, s1.x, s1.y), 0.f);
            vb.x = fmaxf(fmaf(vb.x, s2.x, s2.y), 0.f);
            vb.y = fmaxf(fmaf(vb.y, s3.x, s3.y), 0.f);
            __half2 a = __floats2half2_rn(va.x, va.y);
            __half2 b = __floats2half2_rn(vb.x, vb.y);
            o.x = *(unsigned int*)&a; o.y = *(unsigned int*)&b;
        }
        *(uint2*)&sA[rr][c4 * 4] = o;
    }
    __syncthreads();

    int w = t >> 6, lane = t & 63, q = lane >> 4, ln = lane & 15;
    f32x4 acc[4];
    #pragma unroll
    for (int rt = 0; rt < 4; rt++) acc[rt] = (f32x4){0.f, 0.f, 0.f, 0.f};

    const f16x8* Wv = (const f16x8*)W2t;   // [row 0..63][k-frag]: idx = row*16 + ks*4 + q
    #pragma unroll
    for (int ks = 0; ks < 4; ks++) {
        f16x8 bf = Wv[(w * 16 + ln) * 16 + ks * 4 + q];
        #pragma unroll
        for (int rt = 0; rt < 4; rt++) {
            f16x8 af = *(const f16x8*)&sA[rt * 16 + ln][ks * 32 + q * 8];
            acc[rt] = __builtin_amdgcn_mfma_f32_16x16x32_f16(af, bf, acc[rt], 0, 0, 0);
        }
    }

    int c = w * 16 + ln;
    float bb2 = b2[c];
    #pragma unroll
    for (int rt = 0; rt < 4; rt++) {
        #pragma unroll
        for (int i = 0; i < 4; i++) {
            int r = r0 + rt * 16 + q * 4 + i;
            if (r < N) {
                float o = fmaxf(acc[rt][i] + bb2, 0.f);
                xnew[(size_t)r * DD + c] = o;
                msgout[(size_t)r * DD + c] = __float2half(o + MSG_EPS);
            }
        }
    }
}

// ================= decoder ========================================================
__global__ __launch_bounds__(256) void decode_k(
    const float* __restrict__ xu, const float* __restrict__ xi,
    const int* __restrict__ pu, const int* __restrict__ pi,
    float* __restrict__ out)
{
    int idx = blockIdx.x * 256 + threadIdx.x;
    int b = idx >> 4, lane = idx & 15;
    if (b >= NPRED) return;
    int u = pu[b], it = pi[b];
    float4 a = ((const float4*)(xu + (size_t)u * DD))[lane];
    float4 c = ((const float4*)(xi + (size_t)it * DD))[lane];
    float s = a.x * c.x + a.y * c.y + a.z * c.z + a.w * c.w;
    #pragma unroll
    for (int off = 8; off; off >>= 1) s += __shfl_down(s, off, 16);
    if (lane == 0) out[b] = s;
}

extern "C" void kernel_launch(void* const* d_in, const int* in_sizes, int n_in,
                              void* d_out, int out_size, void* d_ws, size_t ws_size,
                              hipStream_t stream)
{
    const float* x_user = (const float*)d_in[0];
    const float* x_item = (const float*)d_in[1];
    const float* W1    = (const float*)d_in[2];   // [3][2][64][128]
    const float* b1    = (const float*)d_in[3];
    const float* gamma = (const float*)d_in[4];
    const float* beta  = (const float*)d_in[5];
    const float* W2    = (const float*)d_in[6];   // [3][2][128][64]
    const float* b2    = (const float*)d_in[7];
    const int* edge = (const int*)d_in[8];        // [2][E]
    const int* pred = (const int*)d_in[9];        // [2][B]
    float* out = (float*)d_out;

    const int* u_idx = edge;
    const int* i_idx = edge + NEDG;

    // ---- workspace bump allocator (256B aligned chunks) ----
    char* p = (char*)d_ws;
    #define ALLOC(ptr, type, count) \
        type* ptr = (type*)p; p += (((size_t)(count) * sizeof(type)) + 255) & ~(size_t)255;

    ALLOC(deg_i, int, NITM)
    ALLOC(deg_u, int, NUSR)
    ALLOC(gsumAll, double, 12 * 256)             // 6 convs x (gsum[128]|gsq[128])
    size_t zero_span = (char*)p - (char*)deg_i;
    ALLOC(part_i, int, NITM)
    ALLOC(part_u, int, NUSR)
    ALLOC(bsum_i, int, 128)
    ALLOC(bsum_u, int, 128)
    ALLOC(bcur_i, int, 128)
    ALLOC(bcur_u, int, 128)
    ALLOC(rowptr_i, int, NITM + 1)
    ALLOC(rowptr_u, int, NUSR + 1)
    ALLOC(csr_i, int, NEDG)
    ALLOC(csr_u, int, NEDG)
    ALLOC(h1_i, __half, (size_t)NITM * DD2)
    ALLOC(h1_u, __half, (size_t)NUSR * DD2)
    ALLOC(W1t, __half, 6 * 8192)
    ALLOC(W2t, __half, 6 * 8192)
    ALLOC(xu0, float, (size_t)NUSR * DD)
    ALLOC(xu1, float, (size_t)NUSR * DD)
    ALLOC(xi0, float, (size_t)NITM * DD)
    ALLOC(xi1, float, (size_t)NITM * DD)
    ALLOC(msg_u, __half, (size_t)NUSR * DD)
    ALLOC(msg_i0, __half, (size_t)NITM * DD)
    ALLOC(msg_i1, __half, (size_t)NITM * DD)
    #undef ALLOC
    float* xu_buf[2] = {xu0, xu1};
    float* xi_buf[2] = {xi0, xi1};

    // packed pair lists (phase-1 output) alias h1 buffers: pairs are consumed by
    // bscat_k strictly BEFORE aggemm1f_k first writes h1 (same stream).
    int* pair_i = (int*)h1_i;
    int* pair_u = (int*)h1_u;

    // ---- CSR build + converts (once; reused by all 3 layers) ----
    hipMemsetAsync(deg_i, 0, zero_span, stream);
    int eb4 = (NEDG / 4 + 255) / 256;
    count_k<<<eb4, 256, 0, stream>>>(u_idx, i_idx, deg_u, deg_i);

    int nbi = (NITM + SCAN_B - 1) / SCAN_B;   // 49
    int nbu = (NUSR + SCAN_B - 1) / SCAN_B;   // 98
    scan1_k<<<nbi + nbu, SCAN_B, 0, stream>>>(deg_i, deg_u, part_i, part_u,
                                              bsum_i, bsum_u, nbi);
    scan2_k<<<2, 128, 0, stream>>>(bsum_i, bsum_u, nbi, nbu);
    scan3_k<<<nbi + nbu, SCAN_B, 0, stream>>>(deg_i, deg_u, part_i, part_u,
                                              bsum_i, bsum_u, rowptr_i, rowptr_u,
                                              bcur_i, bcur_u, nbi);
    int pb = (NEDG + EPB - 1) / EPB;          // 245
    part_k<<<pb, 256, 0, stream>>>(u_idx, i_idx, bcur_i, bcur_u, pair_i, pair_u);
    bscat_k<<<KI + KU, 1024, 0, stream>>>(pair_i, pair_u, rowptr_i, rowptr_u,
                                          csr_i, csr_u);

    wconv_k<<<(6 * 8192 + 255) / 256, 256, 0, stream>>>(W1, W2, W1t, W2t);
    msg0_k<<<((NUSR + NITM) * 16 + 255) / 256, 256, 0, stream>>>(x_user, x_item,
                                                                 msg_u, msg_i0);

    // ---- 3 layers, each = 1 fused aggemm1 + 1 fused gemm2 ----
    int gI = (NITM + 63) / 64;    // 782 item blocks
    int gU = (NUSR + 63) / 64;    // 1563 user blocks
    const float* cu = x_user;
    const float* ci = x_item;
    __half* msgi = msg_i0;
    __half* msgi_alt = msg_i1;
    for (int l = 0; l < 3; l++) {
        float* ni = xi_buf[l & 1];
        float* nu = xu_buf[l & 1];
        aggemm1f_k<<<gI + gU, 256, 0, stream>>>(
            msgi, msg_u, ci, cu, rowptr_i, rowptr_u, csr_i, csr_u,
            W1t + (size_t)l * 2 * 8192, b1 + (size_t)l * 2 * DD2,
            h1_i, h1_u, gsumAll + l * 2 * 256, gI);
        gemm2f_k<<<gI + gU, 256, 0, stream>>>(
            h1_i, h1_u, gsumAll + l * 2 * 256,
            gamma + (size_t)l * 2 * DD2, beta + (size_t)l * 2 * DD2,
            W2t + (size_t)l * 2 * 8192, b2 + (size_t)l * 2 * DD,
            ni, nu, msgi_alt, msg_u, gI);
        cu = nu; ci = ni;
        __half* tmp = msgi; msgi = msgi_alt; msgi_alt = tmp;
    }

    decode_k<<<(NPRED * 16) / 256, 256, 0, stream>>>(cu, ci, pred, pred + NPRED, out);
}